// Round 6
// baseline (56.888 us; speedup 1.0000x reference)
//
#include <hip/hip_runtime.h>
#include <hip/hip_bf16.h>

#define NROW 4096      // 2B
#define HALFB 2048     // B
#define CDIM 1024
#define INV_T 2.0f     // 1/0.5
#define NBLK16 16      // NROW / 256
#define NTRI16 136     // NBLK16*(NBLK16+1)/2
#define NT 16          // CDIM / 64 K-tiles

typedef __attribute__((ext_vector_type(8))) short bf16x8;
typedef __attribute__((ext_vector_type(4))) float f32x4;

__device__ __forceinline__ float bf2f(unsigned short u) {
    union { unsigned int u; float f; } c; c.u = ((unsigned int)u) << 16; return c.f;
}
__device__ __forceinline__ unsigned short f2bf(float f) {
    __hip_bfloat16 h = __float2bfloat16(f);
    union { __hip_bfloat16 h; unsigned short u; } c; c.h = h; return c.u;
}

// ---------------- Kernel 1: row L2-normalize + bf16 pack (+ zero den) ----------------
__global__ __launch_bounds__(256) void normalize_kernel(
        const float* __restrict__ z1, const float* __restrict__ z2,
        unsigned short* __restrict__ zb, float* __restrict__ den) {
    const int row = blockIdx.x;
    const int t = threadIdx.x;
    if (row < 16) den[row * 256 + t] = 0.f;   // NROW = 16*256; gemm is stream-ordered after
    const float* src = (row < HALFB) ? (z1 + (size_t)row * CDIM)
                                     : (z2 + (size_t)(row - HALFB) * CDIM);
    float4 v = ((const float4*)src)[t];
    float ss = v.x * v.x + v.y * v.y + v.z * v.z + v.w * v.w;
    #pragma unroll
    for (int off = 1; off < 64; off <<= 1) ss += __shfl_xor(ss, off);
    __shared__ float wsum[4];
    const int lane = t & 63, wv = t >> 6;
    if (lane == 0) wsum[wv] = ss;
    __syncthreads();
    const float tot = wsum[0] + wsum[1] + wsum[2] + wsum[3];
    const float scale = 1.0f / fmaxf(sqrtf(tot), 1e-12f);
    ushort4 p;
    p.x = f2bf(v.x * scale);
    p.y = f2bf(v.y * scale);
    p.z = f2bf(v.z * scale);
    p.w = f2bf(v.w * scale);
    ((ushort4*)(zb + (size_t)row * CDIM))[t] = p;
}

// ---------------- Kernel 2: 256^2 triangle GEMM, m201-style 4-phase K-tiles ----------------
// grid = 136 x 512 thr (8 waves 2Mx4N; per-wave 128x64). BK=64 as 2 K-halves.
// Per K-tile: 4 phases, each {ds_read (4 or 8 b128) ; 2 gload_lds ; barrier ;
//   setprio(1) 16 MFMA setprio(0) ; [vmcnt(4) at phases 1,3] ; barrier}.
// Phase quadrant = (M-half mh, K-half kh); b[4] read once per kh, register-reused
// across both mh phases. vmcnt(4) drains the 4 oldest loads (outstanding 8 -> 4):
//   end P1: drains (buf,kh1) [read in P2/P3]; end P3: drains (t+1,kh0) [next P0].
// Loads never drained to 0 in the main loop (T4); flight >= 2 phases.
// Diag blocks stage B redundantly (same panel) to keep vmcnt counts uniform.
// Swizzle: 16B slot ^= (row>>1)&3, on global SOURCE and ds_read (linear LDS dest).
// Rule #20: every acc[][] access compile-time-indexed (R4: scratch spill = 3x).
__global__ __launch_bounds__(512, 2) void gemm_den_kernel(
        const unsigned short* __restrict__ zb, float* __restrict__ den,
        float* __restrict__ pos) {
    __shared__ __align__(16) unsigned short As[2][2][256 * 32];
    __shared__ __align__(16) unsigned short Bs[2][2][256 * 32];

    // XCD swizzle (136 = 8*17, bijective), then triangle decode
    const int orig = blockIdx.x;
    int swz = (orig & 7) * (NTRI16 / 8) + (orig >> 3);
    int bi = 0, rem = swz;
    while (rem >= NBLK16 - bi) { rem -= NBLK16 - bi; ++bi; }
    const int bj = bi + rem;
    const int i0 = bi * 256, j0 = bj * 256;
    const bool diag = (bi == bj);
    const bool is_pos = (bj == bi + NBLK16 / 2);   // tile diagonal holds S[i, i+B]

    const int tid = threadIdx.x;
    const int wave = tid >> 6, lane = tid & 63;
    const int wr = wave >> 2, wc = wave & 3;       // 2 x 4 wave grid; per-wave 128x64

    f32x4 acc[8][4];
    #pragma unroll
    for (int im = 0; im < 8; im++)
        #pragma unroll
        for (int jc = 0; jc < 4; jc++) acc[im][jc] = (f32x4){0.f, 0.f, 0.f, 0.f};

    // staging lane geometry: 16 rows x 32 cols per wave-instruction (1KB)
    const int srow = lane >> 2;                          // 0..15
    const int sslot = (lane & 3) ^ ((lane >> 3) & 3);    // pre-swizzled 16B slot

    // 2 gload_lds: one operand panel's K-half (512 rows-of-16 per wave pair)
    auto stageA = [&](int buf, int kt, int kh) {
        const int k0 = kt * 64 + kh * 32 + sslot * 8;
        #pragma unroll
        for (int q = 0; q < 2; ++q) {
            const int r = q * 128 + wave * 16;           // wave-uniform row base
            const unsigned short* ga = zb + (size_t)(i0 + r + srow) * CDIM + k0;
            __builtin_amdgcn_global_load_lds(
                (const __attribute__((address_space(1))) void*)ga,
                (__attribute__((address_space(3))) void*)&As[buf][kh][r * 32],
                16, 0, 0);
        }
    };
    auto stageB = [&](int buf, int kt, int kh) {
        const int k0 = kt * 64 + kh * 32 + sslot * 8;
        #pragma unroll
        for (int q = 0; q < 2; ++q) {
            const int r = q * 128 + wave * 16;
            const unsigned short* gb = zb + (size_t)(j0 + r + srow) * CDIM + k0;
            __builtin_amdgcn_global_load_lds(
                (const __attribute__((address_space(1))) void*)gb,
                (__attribute__((address_space(3))) void*)&Bs[buf][kh][r * 32],
                16, 0, 0);
        }
    };

    // prologue: K-tile 0, both halves; kh1's 4 loads stay in flight
    stageA(0, 0, 0); stageB(0, 0, 0);
    stageA(0, 0, 1); stageB(0, 0, 1);
    asm volatile("s_waitcnt vmcnt(4)" ::: "memory");
    __builtin_amdgcn_s_barrier();
    __builtin_amdgcn_sched_barrier(0);

    const int l15 = lane & 15, ks = lane >> 4;

    #pragma unroll 1
    for (int t = 0; t < NT; ++t) {
        const int buf = t & 1;
        const bool stg = (t + 1 < NT);
        #pragma unroll
        for (int kh = 0; kh < 2; ++kh) {
            // b-fragments for this K-half (reused across both mh phases)
            bf16x8 b[4];
            #pragma unroll
            for (int jc = 0; jc < 4; ++jc) {
                const int row = wc * 64 + jc * 16 + l15;
                const int slot = ks ^ ((row >> 1) & 3);
                b[jc] = *(const bf16x8*)(&Bs[buf][kh][row * 32 + slot * 8]);
            }
            #pragma unroll
            for (int mh = 0; mh < 2; ++mh) {
                bf16x8 a[4];
                #pragma unroll
                for (int i = 0; i < 4; ++i) {
                    const int row = wr * 128 + (mh * 4 + i) * 16 + l15;
                    const int slot = ks ^ ((row >> 1) & 3);
                    a[i] = *(const bf16x8*)(&As[buf][kh][row * 32 + slot * 8]);
                }
                // stage 2 loads of next K-tile: P0:A(kh0) P1:B(kh0) P2:A(kh1) P3:B(kh1)
                if (stg) {
                    if (mh == 0) stageA(buf ^ 1, t + 1, kh);
                    else         stageB(buf ^ 1, t + 1, kh);
                }
                __builtin_amdgcn_s_barrier();
                __builtin_amdgcn_sched_barrier(0);
                __builtin_amdgcn_s_setprio(1);
                #pragma unroll
                for (int i = 0; i < 4; ++i)
                    #pragma unroll
                    for (int jc = 0; jc < 4; ++jc)
                        acc[mh * 4 + i][jc] = __builtin_amdgcn_mfma_f32_16x16x32_bf16(
                            a[i], b[jc], acc[mh * 4 + i][jc], 0, 0, 0);
                __builtin_amdgcn_s_setprio(0);
                if (mh == 1) {   // drain point: keep 4 newest in flight
                    if (stg)          asm volatile("s_waitcnt vmcnt(4)" ::: "memory");
                    else if (kh == 0) asm volatile("s_waitcnt vmcnt(0)" ::: "memory");
                }
                __builtin_amdgcn_s_barrier();
                __builtin_amdgcn_sched_barrier(0);
            }
        }
    }

    // ---- positives: tiles with j0 == i0 + 2048 hold S[i, i+B] on their diagonal.
    if (is_pos && (wc >> 1) == wr) {
        const int c1 = wc & 1;
        #pragma unroll
        for (int jc = 0; jc < 4; ++jc) {
            #pragma unroll
            for (int r = 0; r < 4; ++r) {
                const float v = c1 ? acc[4 + jc][jc][r] : acc[jc][jc][r];
                if (l15 == ks * 4 + r)
                    pos[i0 + wr * 128 + c1 * 64 + jc * 16 + l15] = v;
            }
        }
    }

    // ---- epilogue: e = exp(2*s); row-sums -> den[i-panel]; col-sums -> den[j-panel]
    float cs[4] = {0.f, 0.f, 0.f, 0.f};
    #pragma unroll
    for (int im = 0; im < 8; ++im) {
        #pragma unroll
        for (int r = 0; r < 4; ++r) {
            float rs = 0.f;
            #pragma unroll
            for (int jc = 0; jc < 4; ++jc) {
                const float e = __expf(INV_T * acc[im][jc][r]);
                rs += e;
                cs[jc] += e;
            }
            rs += __shfl_xor(rs, 1);
            rs += __shfl_xor(rs, 2);
            rs += __shfl_xor(rs, 4);
            rs += __shfl_xor(rs, 8);
            if (l15 == 0) {
                const int grow = i0 + wr * 128 + im * 16 + ks * 4 + r;
                atomicAdd(&den[grow], rs);
            }
        }
    }
    if (!diag) {
        #pragma unroll
        for (int jc = 0; jc < 4; ++jc) {
            float c = cs[jc];
            c += __shfl_xor(c, 16);
            c += __shfl_xor(c, 32);
            if (lane < 16) {
                const int gcol = j0 + wc * 64 + jc * 16 + lane;
                atomicAdd(&den[gcol], c);
            }
        }
    }
}

// ---------------- Kernel 3: final loss ----------------
__global__ __launch_bounds__(256) void loss_kernel(
        const float* __restrict__ den, const float* __restrict__ pos,
        float* __restrict__ out) {
    const float E2 = 7.3890560989306495f;  // exp(2) = diagonal term
    const int tid = threadIdx.x;
    float acc = 0.f;
    for (int i = tid; i < NROW; i += 256)
        acc += INV_T * pos[i & (HALFB - 1)] - logf(den[i] - E2);
    #pragma unroll
    for (int off = 1; off < 64; off <<= 1) acc += __shfl_xor(acc, off);
    __shared__ float wsum[4];
    const int lane = tid & 63, wv = tid >> 6;
    if (lane == 0) wsum[wv] = acc;
    __syncthreads();
    if (tid == 0) out[0] = -(wsum[0] + wsum[1] + wsum[2] + wsum[3]) * (1.0f / NROW);
}

extern "C" void kernel_launch(void* const* d_in, const int* in_sizes, int n_in,
                              void* d_out, int out_size, void* d_ws, size_t ws_size,
                              hipStream_t stream) {
    const float* z1 = (const float*)d_in[0];
    const float* z2 = (const float*)d_in[1];
    float* out = (float*)d_out;

    unsigned short* zb = (unsigned short*)d_ws;                      // 8 MB
    float* den = (float*)((char*)d_ws + (size_t)NROW * CDIM * 2);    // 16 KB
    float* pos = den + NROW;                                         // 8 KB

    normalize_kernel<<<NROW, 256, 0, stream>>>(z1, z2, zb, den);
    gemm_den_kernel<<<NTRI16, 512, 0, stream>>>(zb, den, pos);
    loss_kernel<<<1, 256, 0, stream>>>(den, pos, out);
}

// Round 7
// 50.907 us; speedup vs baseline: 1.1175x; 1.1175x over previous
//
#include <hip/hip_runtime.h>
#include <hip/hip_bf16.h>

#define NROW 4096      // 2B
#define HALFB 2048     // B
#define CDIM 1024
#define INV_T 2.0f     // 1/0.5
#define NBLK 32        // NROW / 128
#define NT 8           // CDIM / 128 K-tiles

typedef __attribute__((ext_vector_type(4))) float f32x4;
typedef __attribute__((ext_vector_type(8))) int i32x8;

// ---------------- Kernel 1: row L2-normalize + fp8(e4m3) pack (+ zero den) ----------------
__global__ __launch_bounds__(256) void normalize_kernel(
        const float* __restrict__ z1, const float* __restrict__ z2,
        unsigned int* __restrict__ zb8, float* __restrict__ den) {
    const int row = blockIdx.x;
    const int t = threadIdx.x;
    if (row < 16) den[row * 256 + t] = 0.f;   // NROW = 16*256; gemm is stream-ordered after
    const float* src = (row < HALFB) ? (z1 + (size_t)row * CDIM)
                                     : (z2 + (size_t)(row - HALFB) * CDIM);
    float4 v = ((const float4*)src)[t];
    float ss = v.x * v.x + v.y * v.y + v.z * v.z + v.w * v.w;
    #pragma unroll
    for (int off = 1; off < 64; off <<= 1) ss += __shfl_xor(ss, off);
    __shared__ float wsum[4];
    const int lane = t & 63, wv = t >> 6;
    if (lane == 0) wsum[wv] = ss;
    __syncthreads();
    const float tot = wsum[0] + wsum[1] + wsum[2] + wsum[3];
    const float scale = 1.0f / fmaxf(sqrtf(tot), 1e-12f);
    // pack 4 floats -> 4 e4m3 bytes (OCP, hardware cvt)
    int w = __builtin_amdgcn_cvt_pk_fp8_f32(v.x * scale, v.y * scale, 0, false);
    w = __builtin_amdgcn_cvt_pk_fp8_f32(v.z * scale, v.w * scale, w, true);
    zb8[(size_t)row * 256 + t] = (unsigned int)w;
}

// ---------------- Kernel 2: full-grid MX-fp8 GEMM + exp + row-sums + pos ----------------
// 1024 blocks (32x32 tiles of 128^2), 256 thr (4 waves 2x2, per-wave 64x64).
// K: 8 tiles of BK=128 via mfma_scale_f32_16x16x128_f8f6f4, unit scales (E8M0 0x7F).
// m97-simple single-buffer loop: stage 32KB -> sync -> 16 MFMA/wave -> sync.
// LDS swizzle: 16B chunk c of row r holds global chunk c^(r&7); applied on the
// gload_lds SOURCE (linear LDS dest) and on ds_read (rule 21). 2-way residual = free.
// Rule #20: all acc indices compile-time.
__global__ __launch_bounds__(256, 2) void gemm_den_kernel(
        const unsigned char* __restrict__ zb8, float* __restrict__ den,
        float* __restrict__ pos) {
    __shared__ __align__(16) unsigned char As[128 * 128];
    __shared__ __align__(16) unsigned char Bs[128 * 128];

    // XCD swizzle (1024 % 8 == 0, bijective); consecutive per-XCD blocks share bi
    const int orig = blockIdx.x;
    const int swz = (orig & 7) * 128 + (orig >> 3);
    const int bi = swz >> 5, bj = swz & 31;
    const int i0 = bi * 128, j0 = bj * 128;
    const bool is_pos = (bj == bi + 16);   // holds S[i, i+B] on its tile diagonal

    const int tid = threadIdx.x;
    const int wave = tid >> 6, lane = tid & 63;
    const int wr = wave >> 1, wc = wave & 1;

    f32x4 acc[4][4];
    #pragma unroll
    for (int m = 0; m < 4; m++)
        #pragma unroll
        for (int n = 0; n < 4; n++) acc[m][n] = (f32x4){0.f, 0.f, 0.f, 0.f};

    // staging geometry: one gload_lds = 8 rows x 128B; lane: row=lane>>3, chunk=lane&7
    const int srow = lane >> 3;                    // 0..7
    const int schunk = (lane & 7) ^ srow;          // pre-swizzled source 16B chunk

    const int l15 = lane & 15, ks = lane >> 4;

    for (int t = 0; t < NT; ++t) {
        const int kb = t * 128;
        #pragma unroll
        for (int c = 0; c < 4; ++c) {
            const int r0 = (wave * 4 + c) * 8;     // wave-uniform row base (0..120)
            const unsigned char* ga =
                zb8 + (size_t)(i0 + r0 + srow) * CDIM + kb + schunk * 16;
            __builtin_amdgcn_global_load_lds(
                (const __attribute__((address_space(1))) void*)ga,
                (__attribute__((address_space(3))) void*)(As + r0 * 128),
                16, 0, 0);
            const unsigned char* gb =
                zb8 + (size_t)(j0 + r0 + srow) * CDIM + kb + schunk * 16;
            __builtin_amdgcn_global_load_lds(
                (const __attribute__((address_space(1))) void*)gb,
                (__attribute__((address_space(3))) void*)(Bs + r0 * 128),
                16, 0, 0);
        }
        __syncthreads();

        // fragments: per lane 32 bytes = k in [ks*32, ks*32+32), row = frag*16 + l15
        i32x8 a[4], b[4];
        #pragma unroll
        for (int m = 0; m < 4; ++m) {
            const int r = wr * 64 + m * 16 + l15;
            const int c0 = (2 * ks) ^ (r & 7);
            const int c1 = (2 * ks + 1) ^ (r & 7);
            const int4 lo = *(const int4*)(As + r * 128 + c0 * 16);
            const int4 hi = *(const int4*)(As + r * 128 + c1 * 16);
            a[m] = (i32x8){lo.x, lo.y, lo.z, lo.w, hi.x, hi.y, hi.z, hi.w};
        }
        #pragma unroll
        for (int n = 0; n < 4; ++n) {
            const int r = wc * 64 + n * 16 + l15;
            const int c0 = (2 * ks) ^ (r & 7);
            const int c1 = (2 * ks + 1) ^ (r & 7);
            const int4 lo = *(const int4*)(Bs + r * 128 + c0 * 16);
            const int4 hi = *(const int4*)(Bs + r * 128 + c1 * 16);
            b[n] = (i32x8){lo.x, lo.y, lo.z, lo.w, hi.x, hi.y, hi.z, hi.w};
        }
        __builtin_amdgcn_s_setprio(1);
        #pragma unroll
        for (int m = 0; m < 4; ++m)
            #pragma unroll
            for (int n = 0; n < 4; ++n)
                acc[m][n] = __builtin_amdgcn_mfma_scale_f32_16x16x128_f8f6f4(
                    a[m], b[n], acc[m][n],
                    0 /*cbsz: A=fp8*/, 0 /*blgp: B=fp8*/,
                    0, 127 /*scaleA byte0 = 2^0*/,
                    0, 127 /*scaleB byte0 = 2^0*/);
        __builtin_amdgcn_s_setprio(0);
        __syncthreads();
    }

    // ---- positives: tiles bj == bi+16 (bi<16) hold S[i, i+B] on their diagonal
    if (is_pos && wr == wc) {
        #pragma unroll
        for (int m = 0; m < 4; ++m) {
            #pragma unroll
            for (int r = 0; r < 4; ++r) {
                if (l15 == ks * 4 + r)
                    pos[i0 + wr * 64 + m * 16 + l15] = acc[m][m][r];
            }
        }
    }

    // ---- epilogue: row-sums of exp(2*s) -> den (diag handled analytically in loss)
    #pragma unroll
    for (int m = 0; m < 4; ++m) {
        #pragma unroll
        for (int r = 0; r < 4; ++r) {
            float rs = 0.f;
            #pragma unroll
            for (int n = 0; n < 4; ++n) rs += __expf(INV_T * acc[m][n][r]);
            rs += __shfl_xor(rs, 1);
            rs += __shfl_xor(rs, 2);
            rs += __shfl_xor(rs, 4);
            rs += __shfl_xor(rs, 8);
            if (l15 == 0) {
                const int grow = i0 + wr * 64 + m * 16 + ks * 4 + r;
                atomicAdd(&den[grow], rs);
            }
        }
    }
}

// ---------------- Kernel 3: final loss ----------------
__global__ __launch_bounds__(256) void loss_kernel(
        const float* __restrict__ den, const float* __restrict__ pos,
        float* __restrict__ out) {
    const float E2 = 7.3890560989306495f;  // exp(2) = diagonal term
    const int tid = threadIdx.x;
    float acc = 0.f;
    for (int i = tid; i < NROW; i += 256)
        acc += INV_T * pos[i & (HALFB - 1)] - logf(den[i] - E2);
    #pragma unroll
    for (int off = 1; off < 64; off <<= 1) acc += __shfl_xor(acc, off);
    __shared__ float wsum[4];
    const int lane = tid & 63, wv = tid >> 6;
    if (lane == 0) wsum[wv] = acc;
    __syncthreads();
    if (tid == 0) out[0] = -(wsum[0] + wsum[1] + wsum[2] + wsum[3]) * (1.0f / NROW);
}

extern "C" void kernel_launch(void* const* d_in, const int* in_sizes, int n_in,
                              void* d_out, int out_size, void* d_ws, size_t ws_size,
                              hipStream_t stream) {
    const float* z1 = (const float*)d_in[0];
    const float* z2 = (const float*)d_in[1];
    float* out = (float*)d_out;

    unsigned int* zb8 = (unsigned int*)d_ws;                         // 4 MB (fp8)
    float* den = (float*)((char*)d_ws + (size_t)NROW * CDIM);        // 16 KB
    float* pos = den + NROW;                                         // 8 KB

    normalize_kernel<<<NROW, 256, 0, stream>>>(z1, z2, zb8, den);
    gemm_den_kernel<<<NBLK * NBLK, 256, 0, stream>>>((const unsigned char*)zb8, den, pos);
    loss_kernel<<<1, 256, 0, stream>>>(den, pos, out);
}